// Round 2
// baseline (999.395 us; speedup 1.0000x reference)
//
#include <hip/hip_runtime.h>
#include <stdint.h>

#define DIM   2048
#define BATCH 4
#define SEQ   4096
#define NTOK  (BATCH*SEQ)      // 16384
#define NCH   128              // cumsum chunks per sequence
#define CHUNK (SEQ/NCH)        // 32 tokens per chunk

// workspace layout (bytes)
#define XB_BYTES   ((size_t)NTOK*DIM*2)          // x in bf16
#define WB_BYTES   ((size_t)4*DIM*DIM*2)         // 4 weights in bf16
#define Y_BYTES    ((size_t)4*NTOK*DIM*2)        // q,k,v,g raw linear outs, bf16
#define PART_BYTES ((size_t)BATCH*NCH*DIM*4)     // chunk partial sums, fp32

typedef __bf16 bf16x8 __attribute__((ext_vector_type(8)));
typedef float  f32x4  __attribute__((ext_vector_type(4)));

__device__ __forceinline__ unsigned short f2bf(float f) {
  unsigned int u = __float_as_uint(f);
  u += 0x7FFFu + ((u >> 16) & 1u);          // round-to-nearest-even
  return (unsigned short)(u >> 16);
}
__device__ __forceinline__ float bflo(unsigned int u){ return __uint_as_float(u << 16); }
__device__ __forceinline__ float bfhi(unsigned int u){ return __uint_as_float(u & 0xFFFF0000u); }
__device__ __forceinline__ float sigm(float x){ return 1.0f/(1.0f + __expf(-x)); }

__device__ __forceinline__ void gload16(const void* g, void* l) {
  __builtin_amdgcn_global_load_lds((const __attribute__((address_space(1))) unsigned int*)g,
                                   (__attribute__((address_space(3))) unsigned int*)l,
                                   16, 0, 0);
}

// ---------------- fp32 -> bf16 conversion (8 elems/thread) ----------------
__global__ void cvt_kernel(const float* __restrict__ src,
                           unsigned short* __restrict__ dst, int n8) {
  int i = blockIdx.x * blockDim.x + threadIdx.x;
  if (i >= n8) return;
  const float4* s4 = (const float4*)src;
  float4 a = s4[2*i], b = s4[2*i+1];
  uint4 o;
  o.x = (unsigned int)f2bf(a.x) | ((unsigned int)f2bf(a.y) << 16);
  o.y = (unsigned int)f2bf(a.z) | ((unsigned int)f2bf(a.w) << 16);
  o.z = (unsigned int)f2bf(b.x) | ((unsigned int)f2bf(b.y) << 16);
  o.w = (unsigned int)f2bf(b.z) | ((unsigned int)f2bf(b.w) << 16);
  ((uint4*)dst)[i] = o;
}

// all 4 weights in one launch; blockIdx.y selects the source
__global__ void cvt_w_kernel(const float* __restrict__ Wq, const float* __restrict__ Wk,
                             const float* __restrict__ Wv, const float* __restrict__ Wg,
                             unsigned short* __restrict__ dst) {
  const int z = blockIdx.y;
  const float* src = (z == 0) ? Wq : (z == 1) ? Wk : (z == 2) ? Wv : Wg;
  int i = blockIdx.x * blockDim.x + threadIdx.x;          // 8-elem chunk index
  const float4* s4 = (const float4*)src;
  float4 a = s4[2*i], b = s4[2*i+1];
  uint4 o;
  o.x = (unsigned int)f2bf(a.x) | ((unsigned int)f2bf(a.y) << 16);
  o.y = (unsigned int)f2bf(a.z) | ((unsigned int)f2bf(a.w) << 16);
  o.z = (unsigned int)f2bf(b.x) | ((unsigned int)f2bf(b.y) << 16);
  o.w = (unsigned int)f2bf(b.z) | ((unsigned int)f2bf(b.w) << 16);
  ((uint4*)(dst + (size_t)z * DIM * DIM))[i] = o;
}

// ---------------- m97-style bf16 GEMM: Y[z] = x @ W[z]^T + b[z] ----------------
// grid (DIM/128, NTOK/128, 4), block 256 (4 waves, each owns 64x64 of the tile)
__global__ __launch_bounds__(256, 2)
void gemm_kernel(const unsigned short* __restrict__ xb,
                 const unsigned short* __restrict__ Wall,
                 const float* __restrict__ bq, const float* __restrict__ bk,
                 const float* __restrict__ bv, const float* __restrict__ bg,
                 unsigned short* __restrict__ Yall) {
  __shared__ __align__(16) unsigned short ldsA[128*32];
  __shared__ __align__(16) unsigned short ldsB[128*32];

  const int t  = threadIdx.x;
  const int e0 = blockIdx.x * 128;
  const int m0 = blockIdx.y * 128;
  const int z  = blockIdx.z;
  const unsigned short* Wz = Wall + (size_t)z * DIM * DIM;

  const int r0 = t >> 2;                    // row 0..63 (second round: +64)
  const int cc = (t & 3) ^ (r0 & 3);        // swizzled 8-elem column chunk
  const unsigned short* gA0 = xb + (size_t)(m0 + r0) * DIM + cc * 8;
  const unsigned short* gA1 = gA0 + (size_t)64 * DIM;
  const unsigned short* gB0 = Wz + (size_t)(e0 + r0) * DIM + cc * 8;
  const unsigned short* gB1 = gB0 + (size_t)64 * DIM;
  unsigned short* lA0 = &ldsA[(size_t)t * 8];
  unsigned short* lA1 = &ldsA[(size_t)(t + 256) * 8];
  unsigned short* lB0 = &ldsB[(size_t)t * 8];
  unsigned short* lB1 = &ldsB[(size_t)(t + 256) * 8];

  const int lane = t & 63;
  const int wave = t >> 6;
  const int wm = wave >> 1, wn = wave & 1;
  const int lr = lane & 15, lq = lane >> 4;
  const int swz8 = (lq ^ (lr & 3)) * 8;
  int aoff[4], boff[4];
  #pragma unroll
  for (int i = 0; i < 4; i++) aoff[i] = (wm*64 + i*16 + lr)*32 + swz8;
  #pragma unroll
  for (int j = 0; j < 4; j++) boff[j] = (wn*64 + j*16 + lr)*32 + swz8;

  f32x4 acc[4][4];
  #pragma unroll
  for (int i = 0; i < 4; i++)
    #pragma unroll
    for (int j = 0; j < 4; j++)
      acc[i][j] = (f32x4){0.f, 0.f, 0.f, 0.f};

  for (int kt = 0; kt < DIM/32; ++kt) {
    __syncthreads();
    const int ko = kt * 32;
    gload16(gA0 + ko, lA0);
    gload16(gA1 + ko, lA1);
    gload16(gB0 + ko, lB0);
    gload16(gB1 + ko, lB1);
    __syncthreads();

    bf16x8 a[4], b[4];
    #pragma unroll
    for (int i = 0; i < 4; i++) a[i] = *(const bf16x8*)&ldsA[aoff[i]];
    #pragma unroll
    for (int j = 0; j < 4; j++) b[j] = *(const bf16x8*)&ldsB[boff[j]];
    #pragma unroll
    for (int i = 0; i < 4; i++)
      #pragma unroll
      for (int j = 0; j < 4; j++)
        acc[i][j] = __builtin_amdgcn_mfma_f32_16x16x32_bf16(a[i], b[j], acc[i][j], 0, 0, 0);
  }

  // epilogue: C/D layout col=lane&15 (=> e), row=(lane>>4)*4+reg (=> token m)
  const float* bias = (z == 0) ? bq : (z == 1) ? bk : (z == 2) ? bv : bg;
  unsigned short* Y = Yall + (size_t)z * NTOK * DIM;
  #pragma unroll
  for (int j = 0; j < 4; j++) {
    const int e = e0 + wn*64 + j*16 + lr;
    const float bb = bias[e];
    #pragma unroll
    for (int i = 0; i < 4; i++) {
      const int mb = m0 + wm*64 + i*16 + lq*4;
      #pragma unroll
      for (int r = 0; r < 4; r++)
        Y[(size_t)(mb + r) * DIM + e] = f2bf(acc[i][j][r] + bb);
    }
  }
}

// ---------------- phase 1: per-chunk partial sums of k*v ----------------
// grid (1, NCH, BATCH), block 256; 8 channels per thread (16B/lane loads)
__global__ void chunk_sum_kernel(const unsigned short* __restrict__ Yk,
                                 const unsigned short* __restrict__ Yv,
                                 float* __restrict__ partial) {
  const int d8 = threadIdx.x;               // uint4 index within row (0..255)
  const int c = blockIdx.y, b = blockIdx.z;
  const size_t base = (size_t)(b*SEQ + c*CHUNK) * (DIM/8) + d8;   // uint4 units
  const uint4* pk = (const uint4*)Yk + base;
  const uint4* pv = (const uint4*)Yv + base;
  float s[8] = {0.f,0.f,0.f,0.f,0.f,0.f,0.f,0.f};
  #pragma unroll 4
  for (int i = 0; i < CHUNK; i++) {
    uint4 ku = pk[(size_t)i*(DIM/8)];
    uint4 vu = pv[(size_t)i*(DIM/8)];
    s[0] += bflo(ku.x)*bflo(vu.x);  s[1] += bfhi(ku.x)*bfhi(vu.x);
    s[2] += bflo(ku.y)*bflo(vu.y);  s[3] += bfhi(ku.y)*bfhi(vu.y);
    s[4] += bflo(ku.z)*bflo(vu.z);  s[5] += bfhi(ku.z)*bfhi(vu.z);
    s[6] += bflo(ku.w)*bflo(vu.w);  s[7] += bfhi(ku.w)*bfhi(vu.w);
  }
  float4* pp = (float4*)(partial + (size_t)(b*NCH + c)*DIM + d8*8);
  pp[0] = make_float4(s[0], s[1], s[2], s[3]);
  pp[1] = make_float4(s[4], s[5], s[6], s[7]);
}

// ---------------- phase 2: exclusive scan of partials along chunks ----------------
__global__ void scan_kernel(float* __restrict__ partial) {
  const int idx = blockIdx.x * blockDim.x + threadIdx.x;  // 0..BATCH*DIM-1
  const int b = idx >> 11;         // / DIM
  const int d = idx & (DIM - 1);
  float run = 0.f;
  for (int c = 0; c < NCH; c++) {
    float* p = partial + (size_t)(b*NCH + c)*DIM + d;
    float tv = *p;
    *p = run;
    run += tv;
  }
}

// ---------------- phase 3: cumsum within chunk + gate + output ----------------
// grid (1, NCH, BATCH), block 256; 8 channels per thread
__global__ void final_kernel(const unsigned short* __restrict__ Yq,
                             const unsigned short* __restrict__ Yk,
                             const unsigned short* __restrict__ Yv,
                             const unsigned short* __restrict__ Yg,
                             const float* __restrict__ partial,
                             float* __restrict__ out) {
  const int d8 = threadIdx.x;               // uint4 index within row (0..255)
  const int c = blockIdx.y, b = blockIdx.z;
  const size_t base = (size_t)(b*SEQ + c*CHUNK) * (DIM/8) + d8;   // uint4 units
  const float4* pst = (const float4*)(partial + (size_t)(b*NCH + c)*DIM + d8*8);
  float4 st0 = pst[0], st1 = pst[1];
  float s[8] = {st0.x, st0.y, st0.z, st0.w, st1.x, st1.y, st1.z, st1.w};
  const uint4* pq = (const uint4*)Yq + base;
  const uint4* pk = (const uint4*)Yk + base;
  const uint4* pv = (const uint4*)Yv + base;
  const uint4* pg = (const uint4*)Yg + base;
  float4* po = (float4*)out + base*2;       // 8 floats per thread per row
  #pragma unroll 2
  for (int i = 0; i < CHUNK; i++) {
    uint4 ku = pk[(size_t)i*(DIM/8)];
    uint4 vu = pv[(size_t)i*(DIM/8)];
    uint4 qu = pq[(size_t)i*(DIM/8)];
    uint4 gu = pg[(size_t)i*(DIM/8)];
    s[0] += bflo(ku.x)*bflo(vu.x);  s[1] += bfhi(ku.x)*bfhi(vu.x);
    s[2] += bflo(ku.y)*bflo(vu.y);  s[3] += bfhi(ku.y)*bfhi(vu.y);
    s[4] += bflo(ku.z)*bflo(vu.z);  s[5] += bfhi(ku.z)*bfhi(vu.z);
    s[6] += bflo(ku.w)*bflo(vu.w);  s[7] += bfhi(ku.w)*bfhi(vu.w);
    float4 o0, o1;
    o0.x = bflo(qu.x)*s[0]*sigm(bflo(gu.x));  o0.y = bfhi(qu.x)*s[1]*sigm(bfhi(gu.x));
    o0.z = bflo(qu.y)*s[2]*sigm(bflo(gu.y));  o0.w = bfhi(qu.y)*s[3]*sigm(bfhi(gu.y));
    o1.x = bflo(qu.z)*s[4]*sigm(bflo(gu.z));  o1.y = bfhi(qu.z)*s[5]*sigm(bfhi(gu.z));
    o1.z = bflo(qu.w)*s[6]*sigm(bflo(gu.w));  o1.w = bfhi(qu.w)*s[7]*sigm(bfhi(gu.w));
    po[(size_t)i*(DIM/4)]     = o0;
    po[(size_t)i*(DIM/4) + 1] = o1;
  }
}

extern "C" void kernel_launch(void* const* d_in, const int* in_sizes, int n_in,
                              void* d_out, int out_size, void* d_ws, size_t ws_size,
                              hipStream_t stream) {
  const float* x  = (const float*)d_in[0];
  const float* Wq = (const float*)d_in[1];
  const float* bq = (const float*)d_in[2];
  const float* Wk = (const float*)d_in[3];
  const float* bk = (const float*)d_in[4];
  const float* Wv = (const float*)d_in[5];
  const float* bv = (const float*)d_in[6];
  const float* Wg = (const float*)d_in[7];
  const float* bg = (const float*)d_in[8];
  float* out = (float*)d_out;

  char* ws = (char*)d_ws;
  unsigned short* xb      = (unsigned short*)(ws);
  unsigned short* Wall    = (unsigned short*)(ws + XB_BYTES);
  unsigned short* Yall    = (unsigned short*)(ws + XB_BYTES + WB_BYTES);
  float*          partial = (float*)(ws + XB_BYTES + WB_BYTES + Y_BYTES);

  // 1) cast inputs to bf16 (2 launches)
  {
    int n8 = NTOK * DIM / 8;
    cvt_kernel<<<n8 / 256, 256, 0, stream>>>(x, xb, n8);
    int w8 = DIM * DIM / 8;
    cvt_w_kernel<<<dim3(w8 / 256, 4), 256, 0, stream>>>(Wq, Wk, Wv, Wg, Wall);
  }

  // 2) four GEMMs (z selects weight): Y[z] = x @ W[z]^T + b[z], bf16 out
  gemm_kernel<<<dim3(DIM/128, NTOK/128, 4), 256, 0, stream>>>(
      xb, Wall, bq, bk, bv, bg, Yall);

  const unsigned short* Yq = Yall + 0*(size_t)NTOK*DIM;
  const unsigned short* Yk = Yall + 1*(size_t)NTOK*DIM;
  const unsigned short* Yv = Yall + 2*(size_t)NTOK*DIM;
  const unsigned short* Yg = Yall + 3*(size_t)NTOK*DIM;

  // 3) chunked cumsum of k*v along seq, then gated output
  chunk_sum_kernel<<<dim3(1, NCH, BATCH), 256, 0, stream>>>(Yk, Yv, partial);
  scan_kernel<<<(BATCH*DIM)/256, 256, 0, stream>>>(partial);
  final_kernel<<<dim3(1, NCH, BATCH), 256, 0, stream>>>(Yq, Yk, Yv, Yg, partial, out);
}

// Round 3
// 895.464 us; speedup vs baseline: 1.1161x; 1.1161x over previous
//
#include <hip/hip_runtime.h>
#include <stdint.h>

#define DIM   2048
#define BATCH 4
#define SEQ   4096
#define NTOK  (BATCH*SEQ)      // 16384
#define NCH   256              // cumsum chunks per sequence
#define CHUNK (SEQ/NCH)        // 16 tokens per chunk

// workspace layout (bytes)
#define XB_BYTES   ((size_t)NTOK*DIM*2)          // x in bf16
#define WB_BYTES   ((size_t)4*DIM*DIM*2)         // 4 weights in bf16
#define PW_BYTES   ((size_t)2*NTOK*DIM*2)        // w = q*sig(g), p = k*v  (bf16)
#define PART_BYTES ((size_t)BATCH*NCH*DIM*4)     // chunk partial sums, fp32

typedef __bf16 bf16x8 __attribute__((ext_vector_type(8)));
typedef float  f32x4  __attribute__((ext_vector_type(4)));

__device__ __forceinline__ unsigned short f2bf(float f) {
  unsigned int u = __float_as_uint(f);
  u += 0x7FFFu + ((u >> 16) & 1u);          // round-to-nearest-even
  return (unsigned short)(u >> 16);
}
__device__ __forceinline__ float bflo(unsigned int u){ return __uint_as_float(u << 16); }
__device__ __forceinline__ float bfhi(unsigned int u){ return __uint_as_float(u & 0xFFFF0000u); }
__device__ __forceinline__ float sigm(float x){ return 1.0f/(1.0f + __expf(-x)); }

__device__ __forceinline__ void gload16(const void* g, void* l) {
  __builtin_amdgcn_global_load_lds((const __attribute__((address_space(1))) unsigned int*)g,
                                   (__attribute__((address_space(3))) unsigned int*)l,
                                   16, 0, 0);
}

// ---------------- fp32 -> bf16 conversion (8 elems/thread) ----------------
__global__ void cvt_kernel(const float* __restrict__ src,
                           unsigned short* __restrict__ dst, int n8) {
  int i = blockIdx.x * blockDim.x + threadIdx.x;
  if (i >= n8) return;
  const float4* s4 = (const float4*)src;
  float4 a = s4[2*i], b = s4[2*i+1];
  uint4 o;
  o.x = (unsigned int)f2bf(a.x) | ((unsigned int)f2bf(a.y) << 16);
  o.y = (unsigned int)f2bf(a.z) | ((unsigned int)f2bf(a.w) << 16);
  o.z = (unsigned int)f2bf(b.x) | ((unsigned int)f2bf(b.y) << 16);
  o.w = (unsigned int)f2bf(b.z) | ((unsigned int)f2bf(b.w) << 16);
  ((uint4*)dst)[i] = o;
}

__global__ void cvt_w_kernel(const float* __restrict__ Wq, const float* __restrict__ Wk,
                             const float* __restrict__ Wv, const float* __restrict__ Wg,
                             unsigned short* __restrict__ dst) {
  const int z = blockIdx.y;
  const float* src = (z == 0) ? Wq : (z == 1) ? Wk : (z == 2) ? Wv : Wg;
  int i = blockIdx.x * blockDim.x + threadIdx.x;
  const float4* s4 = (const float4*)src;
  float4 a = s4[2*i], b = s4[2*i+1];
  uint4 o;
  o.x = (unsigned int)f2bf(a.x) | ((unsigned int)f2bf(a.y) << 16);
  o.y = (unsigned int)f2bf(a.z) | ((unsigned int)f2bf(a.w) << 16);
  o.z = (unsigned int)f2bf(b.x) | ((unsigned int)f2bf(b.y) << 16);
  o.w = (unsigned int)f2bf(b.z) | ((unsigned int)f2bf(b.w) << 16);
  ((uint4*)(dst + (size_t)z * DIM * DIM))[i] = o;
}

// ---------------- z-paired bf16 GEMM with fused pairing epilogue ----------------
// blockIdx.z==0: compute q,g tile -> write w = (q+bq)*sigmoid(g+bg)  (bf16)
// blockIdx.z==1: compute k,v tile -> write p = (k+bk)*(v+bv)         (bf16)
// grid (DIM/128, NTOK/128, 2), block 256 (4 waves, each 64x64 of the tile)
__global__ __launch_bounds__(256, 2)
void gemm_kernel(const unsigned short* __restrict__ xb,
                 const unsigned short* __restrict__ Wall,
                 const float* __restrict__ bq, const float* __restrict__ bk,
                 const float* __restrict__ bv, const float* __restrict__ bg,
                 unsigned short* __restrict__ Yw,
                 unsigned short* __restrict__ Yp) {
  __shared__ __align__(16) unsigned short ldsA [128*32];
  __shared__ __align__(16) unsigned short ldsBa[128*32];
  __shared__ __align__(16) unsigned short ldsBb[128*32];

  const int t  = threadIdx.x;
  const int e0 = blockIdx.x * 128;
  const int m0 = blockIdx.y * 128;
  const int zg = blockIdx.z;                // 0: (q,g)->w   1: (k,v)->p
  const unsigned short* Wa = Wall + (size_t)(zg == 0 ? 0 : 1) * DIM * DIM; // q or k
  const unsigned short* Wb = Wall + (size_t)(zg == 0 ? 3 : 2) * DIM * DIM; // g or v

  const int r0 = t >> 2;                    // row 0..63 (second round: +64)
  const int cc = (t & 3) ^ (r0 & 3);        // swizzled 8-elem column chunk
  const unsigned short* gA0 = xb + (size_t)(m0 + r0) * DIM + cc * 8;
  const unsigned short* gA1 = gA0 + (size_t)64 * DIM;
  const unsigned short* gBa0 = Wa + (size_t)(e0 + r0) * DIM + cc * 8;
  const unsigned short* gBa1 = gBa0 + (size_t)64 * DIM;
  const unsigned short* gBb0 = Wb + (size_t)(e0 + r0) * DIM + cc * 8;
  const unsigned short* gBb1 = gBb0 + (size_t)64 * DIM;
  unsigned short* lA0  = &ldsA [(size_t)t * 8];
  unsigned short* lA1  = &ldsA [(size_t)(t + 256) * 8];
  unsigned short* lBa0 = &ldsBa[(size_t)t * 8];
  unsigned short* lBa1 = &ldsBa[(size_t)(t + 256) * 8];
  unsigned short* lBb0 = &ldsBb[(size_t)t * 8];
  unsigned short* lBb1 = &ldsBb[(size_t)(t + 256) * 8];

  const int lane = t & 63;
  const int wave = t >> 6;
  const int wm = wave >> 1, wn = wave & 1;
  const int lr = lane & 15, lq = lane >> 4;
  const int swz8 = (lq ^ (lr & 3)) * 8;
  int aoff[4], boff[4];
  #pragma unroll
  for (int i = 0; i < 4; i++) aoff[i] = (wm*64 + i*16 + lr)*32 + swz8;
  #pragma unroll
  for (int j = 0; j < 4; j++) boff[j] = (wn*64 + j*16 + lr)*32 + swz8;

  f32x4 accA[4][4], accB[4][4];
  #pragma unroll
  for (int i = 0; i < 4; i++)
    #pragma unroll
    for (int j = 0; j < 4; j++) {
      accA[i][j] = (f32x4){0.f, 0.f, 0.f, 0.f};
      accB[i][j] = (f32x4){0.f, 0.f, 0.f, 0.f};
    }

  for (int kt = 0; kt < DIM/32; ++kt) {
    __syncthreads();
    const int ko = kt * 32;
    gload16(gA0  + ko, lA0);
    gload16(gA1  + ko, lA1);
    gload16(gBa0 + ko, lBa0);
    gload16(gBa1 + ko, lBa1);
    gload16(gBb0 + ko, lBb0);
    gload16(gBb1 + ko, lBb1);
    __syncthreads();

    bf16x8 a[4];
    #pragma unroll
    for (int i = 0; i < 4; i++) a[i] = *(const bf16x8*)&ldsA[aoff[i]];
    {
      bf16x8 b[4];
      #pragma unroll
      for (int j = 0; j < 4; j++) b[j] = *(const bf16x8*)&ldsBa[boff[j]];
      #pragma unroll
      for (int i = 0; i < 4; i++)
        #pragma unroll
        for (int j = 0; j < 4; j++)
          accA[i][j] = __builtin_amdgcn_mfma_f32_16x16x32_bf16(a[i], b[j], accA[i][j], 0, 0, 0);
    }
    {
      bf16x8 b[4];
      #pragma unroll
      for (int j = 0; j < 4; j++) b[j] = *(const bf16x8*)&ldsBb[boff[j]];
      #pragma unroll
      for (int i = 0; i < 4; i++)
        #pragma unroll
        for (int j = 0; j < 4; j++)
          accB[i][j] = __builtin_amdgcn_mfma_f32_16x16x32_bf16(a[i], b[j], accB[i][j], 0, 0, 0);
    }
  }

  // epilogue: C/D layout col=lane&15 (=> e), row=(lane>>4)*4+reg (=> token m)
  const float* biasA = (zg == 0) ? bq : bk;
  const float* biasB = (zg == 0) ? bg : bv;
  unsigned short* Y = (zg == 0) ? Yw : Yp;
  #pragma unroll
  for (int j = 0; j < 4; j++) {
    const int e = e0 + wn*64 + j*16 + lr;
    const float bA = biasA[e];
    const float bB = biasB[e];
    #pragma unroll
    for (int i = 0; i < 4; i++) {
      const int mb = m0 + wm*64 + i*16 + lq*4;
      #pragma unroll
      for (int r = 0; r < 4; r++) {
        const float vA = accA[i][j][r] + bA;
        const float vB = accB[i][j][r] + bB;
        const float val = (zg == 0) ? (vA * sigm(vB)) : (vA * vB);
        Y[(size_t)(mb + r) * DIM + e] = f2bf(val);
      }
    }
  }
}

// ---------------- phase 1: per-chunk partial sums of p ----------------
// grid (1, NCH, BATCH), block 256; 8 channels per thread (16B/lane loads)
__global__ void chunk_sum_kernel(const unsigned short* __restrict__ Yp,
                                 float* __restrict__ partial) {
  const int d8 = threadIdx.x;               // uint4 index within row (0..255)
  const int c = blockIdx.y, b = blockIdx.z;
  const size_t base = (size_t)(b*SEQ + c*CHUNK) * (DIM/8) + d8;
  const uint4* pp = (const uint4*)Yp + base;
  float s[8] = {0.f,0.f,0.f,0.f,0.f,0.f,0.f,0.f};
  #pragma unroll 4
  for (int i = 0; i < CHUNK; i++) {
    uint4 pu = pp[(size_t)i*(DIM/8)];
    s[0] += bflo(pu.x);  s[1] += bfhi(pu.x);
    s[2] += bflo(pu.y);  s[3] += bfhi(pu.y);
    s[4] += bflo(pu.z);  s[5] += bfhi(pu.z);
    s[6] += bflo(pu.w);  s[7] += bfhi(pu.w);
  }
  float4* po = (float4*)(partial + (size_t)(b*NCH + c)*DIM + d8*8);
  po[0] = make_float4(s[0], s[1], s[2], s[3]);
  po[1] = make_float4(s[4], s[5], s[6], s[7]);
}

// ---------------- phase 2: exclusive scan along chunks (wave shfl scan) ----------------
// one wave per (b,d) channel; 4 chunk-values per lane (NCH=256)
__global__ void scan_kernel(float* __restrict__ partial) {
  const int wid  = (blockIdx.x * blockDim.x + threadIdx.x) >> 6;  // 0..BATCH*DIM-1
  const int lane = threadIdx.x & 63;
  const int b = wid >> 11;           // / DIM
  const int d = wid & (DIM - 1);
  float* base = partial + (size_t)b * NCH * DIM + d;
  float v[4];
  #pragma unroll
  for (int k = 0; k < 4; k++) v[k] = base[(size_t)(lane*4 + k) * DIM];
  float sum = v[0] + v[1] + v[2] + v[3];
  float inc = sum;
  #pragma unroll
  for (int off = 1; off < 64; off <<= 1) {
    float n = __shfl_up(inc, off, 64);
    if (lane >= off) inc += n;
  }
  float run = inc - sum;             // exclusive prefix for this lane's group
  #pragma unroll
  for (int k = 0; k < 4; k++) {
    base[(size_t)(lane*4 + k) * DIM] = run;
    run += v[k];
  }
}

// ---------------- phase 3: cumsum within chunk + output = w * state ----------------
// grid (1, NCH, BATCH), block 256; 8 channels per thread
__global__ void final_kernel(const unsigned short* __restrict__ Yw,
                             const unsigned short* __restrict__ Yp,
                             const float* __restrict__ partial,
                             float* __restrict__ out) {
  const int d8 = threadIdx.x;
  const int c = blockIdx.y, b = blockIdx.z;
  const size_t base = (size_t)(b*SEQ + c*CHUNK) * (DIM/8) + d8;
  const float4* pst = (const float4*)(partial + (size_t)(b*NCH + c)*DIM + d8*8);
  float4 st0 = pst[0], st1 = pst[1];
  float s[8] = {st0.x, st0.y, st0.z, st0.w, st1.x, st1.y, st1.z, st1.w};
  const uint4* pw = (const uint4*)Yw + base;
  const uint4* pp = (const uint4*)Yp + base;
  float4* po = (float4*)out + base*2;
  #pragma unroll 2
  for (int i = 0; i < CHUNK; i++) {
    uint4 pu = pp[(size_t)i*(DIM/8)];
    uint4 wu = pw[(size_t)i*(DIM/8)];
    s[0] += bflo(pu.x);  s[1] += bfhi(pu.x);
    s[2] += bflo(pu.y);  s[3] += bfhi(pu.y);
    s[4] += bflo(pu.z);  s[5] += bfhi(pu.z);
    s[6] += bflo(pu.w);  s[7] += bfhi(pu.w);
    float4 o0, o1;
    o0.x = bflo(wu.x)*s[0];  o0.y = bfhi(wu.x)*s[1];
    o0.z = bflo(wu.y)*s[2];  o0.w = bfhi(wu.y)*s[3];
    o1.x = bflo(wu.z)*s[4];  o1.y = bfhi(wu.z)*s[5];
    o1.z = bflo(wu.w)*s[6];  o1.w = bfhi(wu.w)*s[7];
    po[(size_t)i*(DIM/4)]     = o0;
    po[(size_t)i*(DIM/4) + 1] = o1;
  }
}

extern "C" void kernel_launch(void* const* d_in, const int* in_sizes, int n_in,
                              void* d_out, int out_size, void* d_ws, size_t ws_size,
                              hipStream_t stream) {
  const float* x  = (const float*)d_in[0];
  const float* Wq = (const float*)d_in[1];
  const float* bq = (const float*)d_in[2];
  const float* Wk = (const float*)d_in[3];
  const float* bk = (const float*)d_in[4];
  const float* Wv = (const float*)d_in[5];
  const float* bv = (const float*)d_in[6];
  const float* Wg = (const float*)d_in[7];
  const float* bg = (const float*)d_in[8];
  float* out = (float*)d_out;

  char* ws = (char*)d_ws;
  unsigned short* xb      = (unsigned short*)(ws);
  unsigned short* Wall    = (unsigned short*)(ws + XB_BYTES);
  unsigned short* Yw      = (unsigned short*)(ws + XB_BYTES + WB_BYTES);
  unsigned short* Yp      = Yw + (size_t)NTOK * DIM;
  float*          partial = (float*)(ws + XB_BYTES + WB_BYTES + PW_BYTES);

  // 1) cast inputs to bf16
  {
    int n8 = NTOK * DIM / 8;
    cvt_kernel<<<n8 / 256, 256, 0, stream>>>(x, xb, n8);
    int w8 = DIM * DIM / 8;
    cvt_w_kernel<<<dim3(w8 / 256, 4), 256, 0, stream>>>(Wq, Wk, Wv, Wg, Wall);
  }

  // 2) paired GEMMs with fused products: Yw = q*sig(g), Yp = k*v
  gemm_kernel<<<dim3(DIM/128, NTOK/128, 2), 256, 0, stream>>>(
      xb, Wall, bq, bk, bv, bg, Yw, Yp);

  // 3) chunked cumsum of p along seq, then out = w * state
  chunk_sum_kernel<<<dim3(1, NCH, BATCH), 256, 0, stream>>>(Yp, partial);
  scan_kernel<<<(BATCH*DIM*64)/256, 256, 0, stream>>>(partial);
  final_kernel<<<dim3(1, NCH, BATCH), 256, 0, stream>>>(Yw, Yp, partial, out);
}